// Round 6
// baseline (610.364 us; speedup 1.0000x reference)
//
#include <hip/hip_runtime.h>
#include <math.h>

#define NB 512
#define NS 1024
#define NT 52
#define TAG_START 50
#define TAG_END 51

// broadcast lane l's value of x to all lanes (compile-time l -> v_readlane_b32)
__device__ __forceinline__ float lane_bcast(float x, int l) {
  return __int_as_float(__builtin_amdgcn_readlane(__float_as_int(x), l));
}

// __launch_bounds__(64, 1): min 1 wave/EU -> full VGPR budget. Round-1's
// plain (64) let the backend cap at 44 VGPRs and spill Mcol[52] to scratch
// (VALUBusy 8%, 1090 cyc/step). Occupancy is irrelevant here (512 waves on
// 256 CUs = 0.5/SIMD); register residency of Mcol is everything.
extern "C" __global__ void __launch_bounds__(64, 1)
crf_batch_kernel(const float* __restrict__ feats,
                 const unsigned char* __restrict__ mask_u8,
                 const int* __restrict__ tags,
                 const float* __restrict__ trans,
                 double* __restrict__ scores)
{
  __shared__ __align__(16) float ldsv[64];
  const int b = blockIdx.x;
  const int lane = threadIdx.x;

  // ---- detect mask dtype: bool (1 byte) vs int32 (4 byte) ----
  // Every sequence has length >= 1, so under the byte hypothesis
  // mask_u8[i*NS] == 1 for every row i. If any differs -> int32 layout.
  int bad = 0;
  for (int i = lane; i < NB; i += 64) bad |= (mask_u8[(size_t)i * NS] != 1u);
  const bool int_mode = (__any(bad) != 0);

  // ---- sequence length of row b (prefix mask sum) ----
  int len = 0;
  if (int_mode) {
    const int* mi = (const int*)mask_u8;
    for (int s = lane; s < NS; s += 64) len += mi[b * NS + s];
  } else {
    for (int s = lane; s < NS; s += 64) len += (int)mask_u8[b * NS + s];
  }
  #pragma unroll
  for (int off = 32; off > 0; off >>= 1) len += __shfl_xor(len, off, 64);

  // ---- per-lane column j of M = exp(transitions): Mcol[i] = exp(T[i][j]) ----
  const int j = (lane < NT) ? lane : 0;
  float Mcol[NT];
  #pragma unroll
  for (int i = 0; i < NT; ++i)
    Mcol[i] = (lane < NT) ? __expf(trans[i * NT + j]) : 0.f;

  const float* fb = feats + (size_t)b * NS * NT;

  // ---- init (s = 0): part0[j] = f0[j] + trans[START][j]; v = exp(part0 - c0) ----
  float p0 = (lane < NT) ? (fb[lane] + trans[TAG_START * NT + lane]) : -1e30f;
  float c0 = p0;
  #pragma unroll
  for (int off = 32; off > 0; off >>= 1) c0 = fmaxf(c0, __shfl_xor(c0, off, 64));
  float v = (lane < NT) ? __expf(p0 - c0) : 0.f;
  int kacc = 0;  // accumulated power-of-2 normalizer (exact)

  // ---- 4-deep emission prefetch (feats L3-resident after iter 1) ----
  const float* frow = fb + j;
  float fp0, fp1, fp2, fp3;
  {
    fp0 = frow[1 * NT]; fp1 = frow[2 * NT];
    fp2 = frow[3 * NT]; fp3 = frow[4 * NT];
  }

  // ---- forward recursion, exp domain: v <- exp(f) * (M^T v) ----
  // State broadcast via LDS: one ds_write_b32 + 13 same-address ds_read_b128
  // (same-address reads broadcast conflict-free) instead of 52 v_readlane.
  for (int s = 1; s < len; ++s) {
    ldsv[lane] = v;
    __syncthreads();   // 1-wave block: compiles to the lgkmcnt fence we need

    float f = fp0;
    fp0 = fp1; fp1 = fp2; fp2 = fp3;
    int sp = (s + 4 < NS) ? (s + 4) : (NS - 1);
    fp3 = frow[sp * NT];

    const float4* lv = (const float4*)ldsv;
    float a0 = 0.f, a1 = 0.f, a2 = 0.f, a3 = 0.f;
    #pragma unroll
    for (int p = 0; p < NT / 4; ++p) {
      float4 vb = lv[p];
      a0 = fmaf(vb.x, Mcol[4 * p + 0], a0);
      a1 = fmaf(vb.y, Mcol[4 * p + 1], a1);
      a2 = fmaf(vb.z, Mcol[4 * p + 2], a2);
      a3 = fmaf(vb.w, Mcol[4 * p + 3], a3);
    }
    float nv = __expf(f) * ((a0 + a1) + (a2 + a3));

    // renorm every 4 steps by the wave-max exponent. Power-of-2 scaling is
    // exact (commutes with fma rounding) -> result stays bit-identical.
    // Growth bound: <= 2^57 over 4 steps, far from f32 overflow.
    if ((s & 3) == 0) {
      float m = nv;
      #pragma unroll
      for (int off = 32; off > 0; off >>= 1) m = fmaxf(m, __shfl_xor(m, off, 64));
      int K = ((__float_as_int(m) >> 23) & 0xff) - 127;
      nv = ldexpf(nv, -K);
      kacc += K;
    }
    v = nv;
    // no second barrier needed: DS ops from one wave execute in issue order,
    // and nv (the next ds_write's data) depends on this step's ds_reads, so
    // write-after-read is already serialized.
  }

  // ---- final: forward_b = c0 + kacc*ln2 + log(sum_i v[i] * M[i][END]) ----
  ldsv[lane] = v;
  __syncthreads();
  {
    const float4* lv = (const float4*)ldsv;
    float e0 = 0.f, e1 = 0.f, e2 = 0.f, e3 = 0.f;
    #pragma unroll
    for (int p = 0; p < NT / 4; ++p) {
      float4 vb = lv[p];
      e0 = fmaf(vb.x, Mcol[4 * p + 0], e0);
      e1 = fmaf(vb.y, Mcol[4 * p + 1], e1);
      e2 = fmaf(vb.z, Mcol[4 * p + 2], e2);
      e3 = fmaf(vb.w, Mcol[4 * p + 3], e3);
    }
    float fin  = __logf((e0 + e1) + (e2 + e3));   // valid on lane j == END
    float finU = lane_bcast(fin, TAG_END);
    double fwd = (double)c0 + (double)kacc * 0.6931471805599453 + (double)finU;

    // ---- gold path score ----
    float g = 0.f;
    for (int s = lane; s < len; s += 64) {
      int tg = tags[b * NS + s];
      int pv = (s == 0) ? TAG_START : tags[b * NS + s - 1];
      g += fb[s * NT + tg] + trans[pv * NT + tg];
    }
    #pragma unroll
    for (int off = 32; off > 0; off >>= 1) g += __shfl_xor(g, off, 64);
    int lastTag = tags[b * NS + (len - 1)];
    double gold = (double)g + (double)trans[lastTag * NT + TAG_END];

    if (lane == 0) scores[b] = fwd - gold;
  }
}

extern "C" __global__ void __launch_bounds__(512)
crf_reduce_kernel(const double* __restrict__ scores, float* __restrict__ out)
{
  __shared__ double sh[8];
  int t = threadIdx.x;
  double x = scores[t];
  #pragma unroll
  for (int off = 32; off > 0; off >>= 1) x += __shfl_xor(x, off, 64);
  if ((t & 63) == 0) sh[t >> 6] = x;
  __syncthreads();
  if (t == 0) {
    double tot = 0.0;
    #pragma unroll
    for (int w = 0; w < 8; ++w) tot += sh[w];
    out[0] = (float)tot;
  }
}

extern "C" void kernel_launch(void* const* d_in, const int* in_sizes, int n_in,
                              void* d_out, int out_size, void* d_ws, size_t ws_size,
                              hipStream_t stream) {
  const float*         feats = (const float*)d_in[0];
  const unsigned char* mask  = (const unsigned char*)d_in[1];
  const int*           tags  = (const int*)d_in[2];
  const float*         trans = (const float*)d_in[3];
  double* scores = (double*)d_ws;   // 512 doubles = 4 KB scratch

  crf_batch_kernel<<<NB, 64, 0, stream>>>(feats, mask, tags, trans, scores);
  crf_reduce_kernel<<<1, 512, 0, stream>>>(scores, (float*)d_out);
}

// Round 7
// 608.890 us; speedup vs baseline: 1.0024x; 1.0024x over previous
//
#include <hip/hip_runtime.h>
#include <math.h>

#define NB 512
#define NS 1024
#define NT 52
#define TAG_START 50
#define TAG_END 51

typedef float f4 __attribute__((ext_vector_type(4)));

// broadcast lane l's value of x to all lanes (compile-time l -> v_readlane_b32)
__device__ __forceinline__ float lane_bcast(float x, int l) {
  return __int_as_float(__builtin_amdgcn_readlane(__float_as_int(x), l));
}

// M column held in 13 NAMED f32x4 registers, NOT a float[52] array.
// Rounds 1-2 evidence: a 52-float local array never gets SROA-promoted
// (VGPR_Count stuck at 44 regardless of __launch_bounds__) -> lives in
// scratch -> 52 scratch loads/step -> 1090 cyc/step, VALUBusy 8%.
// Named ext-vector variables are guaranteed SSA -> guaranteed VGPRs.
extern "C" __global__ void __launch_bounds__(64, 1)
crf_batch_kernel(const float* __restrict__ feats,
                 const unsigned char* __restrict__ mask_u8,
                 const int* __restrict__ tags,
                 const float* __restrict__ trans,
                 double* __restrict__ scores)
{
  __shared__ __align__(16) float ldsv[64];
  const int b = blockIdx.x;
  const int lane = threadIdx.x;

  // ---- detect mask dtype: bool (1 byte) vs int32 (4 byte) ----
  // Every sequence has length >= 1, so under the byte hypothesis
  // mask_u8[i*NS] == 1 for every row i. If any differs -> int32 layout.
  int bad = 0;
  for (int i = lane; i < NB; i += 64) bad |= (mask_u8[(size_t)i * NS] != 1u);
  const bool int_mode = (__any(bad) != 0);

  // ---- sequence length of row b (prefix mask sum) ----
  int len = 0;
  if (int_mode) {
    const int* mi = (const int*)mask_u8;
    for (int s = lane; s < NS; s += 64) len += mi[b * NS + s];
  } else {
    for (int s = lane; s < NS; s += 64) len += (int)mask_u8[b * NS + s];
  }
  #pragma unroll
  for (int off = 32; off > 0; off >>= 1) len += __shfl_xor(len, off, 64);

  // ---- column j of M = exp(transitions) in 13 named f32x4 registers ----
  const bool on = (lane < NT);
  const int j = on ? lane : 0;
  const float* tj = trans + j;
#define LDM(p)                                              \
  f4 M##p;                                                  \
  M##p.x = on ? __expf(tj[(4 * (p) + 0) * NT]) : 0.f;       \
  M##p.y = on ? __expf(tj[(4 * (p) + 1) * NT]) : 0.f;       \
  M##p.z = on ? __expf(tj[(4 * (p) + 2) * NT]) : 0.f;       \
  M##p.w = on ? __expf(tj[(4 * (p) + 3) * NT]) : 0.f;
  LDM(0) LDM(1) LDM(2) LDM(3) LDM(4) LDM(5) LDM(6)
  LDM(7) LDM(8) LDM(9) LDM(10) LDM(11) LDM(12)
#undef LDM

  const float* fb = feats + (size_t)b * NS * NT;

  // ---- init (s = 0): part0[j] = f0[j] + trans[START][j]; v = exp(part0 - c0) ----
  float p0 = on ? (fb[lane] + trans[TAG_START * NT + lane]) : -1e30f;
  float c0 = p0;
  #pragma unroll
  for (int off = 32; off > 0; off >>= 1) c0 = fmaxf(c0, __shfl_xor(c0, off, 64));
  float v = on ? __expf(p0 - c0) : 0.f;
  int kacc = 0;  // accumulated power-of-2 normalizer (exact)

  // ---- 4-deep emission prefetch (feats L3-resident after iter 1) ----
  const float* frow = fb + j;
  float fp0 = frow[1 * NT], fp1 = frow[2 * NT];
  float fp2 = frow[3 * NT], fp3 = frow[4 * NT];

  const f4* lv = (const f4*)ldsv;

  // one i-block of the matvec: acc += vbroadcast[4p..4p+3] * Mcol[4p..4p+3]
#define ACC4(p)                              \
  {                                          \
    f4 vb = lv[p];                           \
    acc.x = fmaf(vb.x, M##p.x, acc.x);       \
    acc.y = fmaf(vb.y, M##p.y, acc.y);       \
    acc.z = fmaf(vb.z, M##p.z, acc.z);       \
    acc.w = fmaf(vb.w, M##p.w, acc.w);       \
  }

  // ---- forward recursion, exp domain: v <- exp(f) * (M^T v) ----
  // State broadcast via LDS: one ds_write_b32 + 13 same-address ds_read_b128
  // (same-address reads broadcast conflict-free).
  for (int s = 1; s < len; ++s) {
    ldsv[lane] = v;
    __syncthreads();   // 1-wave block: the lgkmcnt fence + cheap barrier

    float f = fp0;
    fp0 = fp1; fp1 = fp2; fp2 = fp3;
    int sp = (s + 4 < NS) ? (s + 4) : (NS - 1);
    fp3 = frow[sp * NT];

    f4 acc = {0.f, 0.f, 0.f, 0.f};
    ACC4(0) ACC4(1) ACC4(2) ACC4(3) ACC4(4) ACC4(5) ACC4(6)
    ACC4(7) ACC4(8) ACC4(9) ACC4(10) ACC4(11) ACC4(12)
    float nv = __expf(f) * ((acc.x + acc.y) + (acc.z + acc.w));

    // renorm every 4 steps by the wave-max exponent. Power-of-2 scaling is
    // exact (commutes with fma rounding) -> result stays bit-identical.
    // Growth bound: <= 2^57 over 4 steps, far from f32 overflow.
    if ((s & 3) == 0) {
      float m = nv;
      #pragma unroll
      for (int off = 32; off > 0; off >>= 1) m = fmaxf(m, __shfl_xor(m, off, 64));
      int K = ((__float_as_int(m) >> 23) & 0xff) - 127;
      nv = ldexpf(nv, -K);
      kacc += K;
    }
    v = nv;
    // no second barrier needed: DS ops from one wave execute in issue order,
    // and nv (the next ds_write's data) depends on this step's ds_reads, so
    // write-after-read is already serialized.
  }

  // ---- final: forward_b = c0 + kacc*ln2 + log(sum_i v[i] * M[i][END]) ----
  ldsv[lane] = v;
  __syncthreads();
  {
    f4 acc = {0.f, 0.f, 0.f, 0.f};
    ACC4(0) ACC4(1) ACC4(2) ACC4(3) ACC4(4) ACC4(5) ACC4(6)
    ACC4(7) ACC4(8) ACC4(9) ACC4(10) ACC4(11) ACC4(12)
    float fin  = __logf((acc.x + acc.y) + (acc.z + acc.w)); // valid on lane END
    float finU = lane_bcast(fin, TAG_END);
    double fwd = (double)c0 + (double)kacc * 0.6931471805599453 + (double)finU;

    // ---- gold path score ----
    float g = 0.f;
    for (int s = lane; s < len; s += 64) {
      int tg = tags[b * NS + s];
      int pv = (s == 0) ? TAG_START : tags[b * NS + s - 1];
      g += fb[s * NT + tg] + trans[pv * NT + tg];
    }
    #pragma unroll
    for (int off = 32; off > 0; off >>= 1) g += __shfl_xor(g, off, 64);
    int lastTag = tags[b * NS + (len - 1)];
    double gold = (double)g + (double)trans[lastTag * NT + TAG_END];

    if (lane == 0) scores[b] = fwd - gold;
  }
#undef ACC4
}

extern "C" __global__ void __launch_bounds__(512)
crf_reduce_kernel(const double* __restrict__ scores, float* __restrict__ out)
{
  __shared__ double sh[8];
  int t = threadIdx.x;
  double x = scores[t];
  #pragma unroll
  for (int off = 32; off > 0; off >>= 1) x += __shfl_xor(x, off, 64);
  if ((t & 63) == 0) sh[t >> 6] = x;
  __syncthreads();
  if (t == 0) {
    double tot = 0.0;
    #pragma unroll
    for (int w = 0; w < 8; ++w) tot += sh[w];
    out[0] = (float)tot;
  }
}

extern "C" void kernel_launch(void* const* d_in, const int* in_sizes, int n_in,
                              void* d_out, int out_size, void* d_ws, size_t ws_size,
                              hipStream_t stream) {
  const float*         feats = (const float*)d_in[0];
  const unsigned char* mask  = (const unsigned char*)d_in[1];
  const int*           tags  = (const int*)d_in[2];
  const float*         trans = (const float*)d_in[3];
  double* scores = (double*)d_ws;   // 512 doubles = 4 KB scratch

  crf_batch_kernel<<<NB, 64, 0, stream>>>(feats, mask, tags, trans, scores);
  crf_reduce_kernel<<<1, 512, 0, stream>>>(scores, (float*)d_out);
}

// Round 8
// 540.800 us; speedup vs baseline: 1.1286x; 1.1259x over previous
//
#include <hip/hip_runtime.h>
#include <math.h>

#define NB 512
#define NS 1024
#define NT 52
#define TAG_START 50
#define TAG_END 51

typedef float f4 __attribute__((ext_vector_type(4)));

// broadcast lane l's value of x to all lanes (compile-time l -> v_readlane_b32)
__device__ __forceinline__ float lane_bcast(float x, int l) {
  return __int_as_float(__builtin_amdgcn_readlane(__float_as_int(x), l));
}

// Evidence trail (rounds 1/6/7 all ~470-490us, VGPR_Count==44, VALUBusy 7-8%,
// no scratch traffic): the compiler REMATERIALIZES M = exp(trans[i][j]) inside
// the step loop (re-load from L1 + v_exp on the trans pipe, invisible to
// VALUBusy) instead of keeping 52 floats live. Fix: pin M via inline asm so
// its definition is un-rematerializable; drop LDS+barrier from the loop
// (readlane broadcast); move exp(f) off the critical chain; renorm via exact
// pow2 constants (no shuffle butterfly in the loop).
extern "C" __global__ void __launch_bounds__(64, 1)
crf_batch_kernel(const float* __restrict__ feats,
                 const unsigned char* __restrict__ mask_u8,
                 const int* __restrict__ tags,
                 const float* __restrict__ trans,
                 double* __restrict__ scores)
{
  const int b = blockIdx.x;
  const int lane = threadIdx.x;

  // ---- detect mask dtype: bool (1 byte) vs int32 (4 byte) ----
  int bad = 0;
  for (int i = lane; i < NB; i += 64) bad |= (mask_u8[(size_t)i * NS] != 1u);
  const bool int_mode = (__any(bad) != 0);

  // ---- sequence length of row b (prefix mask sum) ----
  int len = 0;
  if (int_mode) {
    const int* mi = (const int*)mask_u8;
    for (int s = lane; s < NS; s += 64) len += mi[b * NS + s];
  } else {
    for (int s = lane; s < NS; s += 64) len += (int)mask_u8[b * NS + s];
  }
  #pragma unroll
  for (int off = 32; off > 0; off >>= 1) len += __shfl_xor(len, off, 64);

  // ---- column j of M = exp(transitions) in 13 named f32x4 registers ----
  // Lanes >= NT alias column 0; they then replicate lane 0's computation
  // exactly (finite, harmless, never read: readlane targets are 0..51).
  const int j = (lane < NT) ? lane : 0;
  const float* tj = trans + j;
#define LDM(p)                                   \
  f4 M##p;                                       \
  M##p.x = __expf(tj[(4 * (p) + 0) * NT]);       \
  M##p.y = __expf(tj[(4 * (p) + 1) * NT]);       \
  M##p.z = __expf(tj[(4 * (p) + 2) * NT]);       \
  M##p.w = __expf(tj[(4 * (p) + 3) * NT]);
  LDM(0) LDM(1) LDM(2) LDM(3) LDM(4) LDM(5) LDM(6)
  LDM(7) LDM(8) LDM(9) LDM(10) LDM(11) LDM(12)
#undef LDM
  // Pin: definitions now come from the asm -> cannot be rematerialized from
  // trans-loads inside the loop; allocator must keep them in VGPRs.
  asm volatile("" : "+v"(M0), "+v"(M1), "+v"(M2), "+v"(M3), "+v"(M4),
                    "+v"(M5), "+v"(M6), "+v"(M7), "+v"(M8), "+v"(M9),
                    "+v"(M10), "+v"(M11), "+v"(M12));

  const float* fb = feats + (size_t)b * NS * NT;

  // ---- init (s = 0): part0[j] = f0[j] + trans[START][j]; w = exp(part0 - c0) ----
  float p0 = (lane < NT) ? (fb[lane] + trans[TAG_START * NT + lane]) : -1e30f;
  float c0 = p0;
  #pragma unroll
  for (int off = 32; off > 0; off >>= 1) c0 = fmaxf(c0, __shfl_xor(c0, off, 64));
  float w = (lane < NT) ? __expf(p0 - c0) : 0.f;
  // lanes >= NT: w = 0 initially, but they recompute lane0's value from step 1
  // (same M col, same broadcasts, same f) -> always finite.
  int kacc = 0;  // accumulated power-of-2 normalizer (exact)

  // ---- emission pipeline: loads 6 ahead (fr0..fr3), exp 2 ahead (er0,er1) ----
  const float* frow = fb + j;
  float er0 = __expf(frow[1 * NT]);
  float er1 = __expf(frow[2 * NT]);
  float fr0 = frow[3 * NT], fr1 = frow[4 * NT];
  float fr2 = frow[5 * NT], fr3 = frow[6 * NT];

  // one 4-row block of the matvec: acc_c += w[4p+c] * Mcol[4p+c]
#define B4(p)                                                  \
  {                                                            \
    acc0 = fmaf(lane_bcast(w, 4 * (p) + 0), M##p.x, acc0);     \
    acc1 = fmaf(lane_bcast(w, 4 * (p) + 1), M##p.y, acc1);     \
    acc2 = fmaf(lane_bcast(w, 4 * (p) + 2), M##p.z, acc2);     \
    acc3 = fmaf(lane_bcast(w, 4 * (p) + 3), M##p.w, acc3);     \
  }

  // ---- forward recursion, exp domain: w <- exp(f) * (M^T w) * 2^-6 ----
  for (int s = 1; s < len; ++s) {
    float ef = er0;
    er0 = er1;
    er1 = __expf(fr0);                       // 2 steps ahead of use
    fr0 = fr1; fr1 = fr2; fr2 = fr3;
    int sp = (s + 6 < NS) ? (s + 6) : (NS - 1);
    fr3 = frow[sp * NT];                     // 6 steps ahead of use

    float acc0 = 0.f, acc1 = 0.f, acc2 = 0.f, acc3 = 0.f;
    B4(0) B4(1) B4(2) B4(3) B4(4) B4(5) B4(6)
    B4(7) B4(8) B4(9) B4(10) B4(11) B4(12)
    // constant 2^-6 per step (typical growth ~52*E[e^f] ~ 2^6); exact pow2.
    float nv = (ef * ((acc0 + acc1) + (acc2 + acc3))) * 0.015625f;
    kacc += 6;

    // every 4 steps: re-center on lane 0's exponent (exact pow2; one-step
    // mixing bounds max/lane0 <= ~2^19, so no overflow/underflow risk).
    if ((s & 3) == 0) {
      float n0 = lane_bcast(nv, 0);
      int K = ((__float_as_int(n0) >> 23) & 0xff) - 127;
      nv = nv * __int_as_float((127 - K) << 23);   // exact * 2^-K
      kacc += K;
    }
    w = nv;
  }

  // ---- final: forward_b = c0 + kacc*ln2 + log(sum_i w[i] * M[i][END]) ----
  {
    float acc0 = 0.f, acc1 = 0.f, acc2 = 0.f, acc3 = 0.f;
    B4(0) B4(1) B4(2) B4(3) B4(4) B4(5) B4(6)
    B4(7) B4(8) B4(9) B4(10) B4(11) B4(12)
    float fin  = __logf((acc0 + acc1) + (acc2 + acc3));  // valid on lane END
    float finU = lane_bcast(fin, TAG_END);
    double fwd = (double)c0 + (double)kacc * 0.6931471805599453 + (double)finU;

    // ---- gold path score ----
    float g = 0.f;
    for (int s = lane; s < len; s += 64) {
      int tg = tags[b * NS + s];
      int pv = (s == 0) ? TAG_START : tags[b * NS + s - 1];
      g += fb[s * NT + tg] + trans[pv * NT + tg];
    }
    #pragma unroll
    for (int off = 32; off > 0; off >>= 1) g += __shfl_xor(g, off, 64);
    int lastTag = tags[b * NS + (len - 1)];
    double gold = (double)g + (double)trans[lastTag * NT + TAG_END];

    if (lane == 0) scores[b] = fwd - gold;
  }
#undef B4
}

extern "C" __global__ void __launch_bounds__(512)
crf_reduce_kernel(const double* __restrict__ scores, float* __restrict__ out)
{
  __shared__ double sh[8];
  int t = threadIdx.x;
  double x = scores[t];
  #pragma unroll
  for (int off = 32; off > 0; off >>= 1) x += __shfl_xor(x, off, 64);
  if ((t & 63) == 0) sh[t >> 6] = x;
  __syncthreads();
  if (t == 0) {
    double tot = 0.0;
    #pragma unroll
    for (int w = 0; w < 8; ++w) tot += sh[w];
    out[0] = (float)tot;
  }
}

extern "C" void kernel_launch(void* const* d_in, const int* in_sizes, int n_in,
                              void* d_out, int out_size, void* d_ws, size_t ws_size,
                              hipStream_t stream) {
  const float*         feats = (const float*)d_in[0];
  const unsigned char* mask  = (const unsigned char*)d_in[1];
  const int*           tags  = (const int*)d_in[2];
  const float*         trans = (const float*)d_in[3];
  double* scores = (double*)d_ws;   // 512 doubles = 4 KB scratch

  crf_batch_kernel<<<NB, 64, 0, stream>>>(feats, mask, tags, trans, scores);
  crf_reduce_kernel<<<1, 512, 0, stream>>>(scores, (float*)d_out);
}

// Round 9
// 374.195 us; speedup vs baseline: 1.6311x; 1.4452x over previous
//
#include <hip/hip_runtime.h>
#include <math.h>

#define NB 512
#define NS 1024
#define NT 52
#define TAG_START 50
#define TAG_END 51
#define TILE 32                 // steps per LDS emission tile
#define TILE_BYTES (TILE * NT * 4)   // 6656
#define LDS_TILE_F 1792              // 7168 B per buffer (7 x 1KB staging chunks)

typedef float f4 __attribute__((ext_vector_type(4)));
typedef __attribute__((address_space(1))) const unsigned int gu32;
typedef __attribute__((address_space(3))) unsigned int lu32;

__device__ __forceinline__ float lane_bcast(float x, int l) {
  return __int_as_float(__builtin_amdgcn_readlane(__float_as_int(x), l));
}

// Evidence trail:
//  r1/r6/r7 (~480us, VGPR 44, VALUBusy 8%): M=exp(trans) rematerialized in-loop.
//    FIXED r8 via asm pin (VGPR 64, -68us). Keep the pin.
//  r8 (415us, VALUBusy 9.4%): 970 cyc/step with only ~90 cyc VALU -> emission
//    load latency fully exposed (rotating-reg prefetch forces vmcnt wait on the
//    previous iteration's load -> depth 1; ~30% HBM misses at ~900 cyc).
//  r9: emissions staged in double-buffered LDS tiles (global_load_lds), one
//    counted vmcnt(7) per 32-step tile; recurrence reads LDS only.
extern "C" __global__ void __launch_bounds__(64, 1)
crf_batch_kernel(const float* __restrict__ feats,
                 const unsigned char* __restrict__ mask_u8,
                 const int* __restrict__ tags,
                 const float* __restrict__ trans,
                 double* __restrict__ scores)
{
  __shared__ __align__(16) float emlds[2 * LDS_TILE_F];   // 14336 B
  const int b = blockIdx.x;
  const int lane = threadIdx.x;

  // ---- detect mask dtype: bool (1 byte) vs int32 (4 byte) ----
  int bad = 0;
  for (int i = lane; i < NB; i += 64) bad |= (mask_u8[(size_t)i * NS] != 1u);
  const bool int_mode = (__any(bad) != 0);

  // ---- sequence length of row b (prefix mask sum) ----
  int len = 0;
  if (int_mode) {
    const int* mi = (const int*)mask_u8;
    for (int s = lane; s < NS; s += 64) len += mi[b * NS + s];
  } else {
    for (int s = lane; s < NS; s += 64) len += (int)mask_u8[b * NS + s];
  }
  #pragma unroll
  for (int off = 32; off > 0; off >>= 1) len += __shfl_xor(len, off, 64);

  // ---- column j of M = exp(transitions), 13 named f32x4, asm-pinned ----
  const int j = (lane < NT) ? lane : 0;
  const float* tj = trans + j;
#define LDM(p)                                   \
  f4 M##p;                                       \
  M##p.x = __expf(tj[(4 * (p) + 0) * NT]);       \
  M##p.y = __expf(tj[(4 * (p) + 1) * NT]);       \
  M##p.z = __expf(tj[(4 * (p) + 2) * NT]);       \
  M##p.w = __expf(tj[(4 * (p) + 3) * NT]);
  LDM(0) LDM(1) LDM(2) LDM(3) LDM(4) LDM(5) LDM(6)
  LDM(7) LDM(8) LDM(9) LDM(10) LDM(11) LDM(12)
#undef LDM
  asm volatile("" : "+v"(M0), "+v"(M1), "+v"(M2), "+v"(M3), "+v"(M4),
                    "+v"(M5), "+v"(M6), "+v"(M7), "+v"(M8), "+v"(M9),
                    "+v"(M10), "+v"(M11), "+v"(M12));

  const float* fb = feats + (size_t)b * NS * NT;
  // clamp for the 512B staging overrun of the last tile (b==511 would fault)
  const char* gclamp = (const char*)feats + (size_t)NB * NS * NT * 4 - 16;

  // stage tile t (7 x 1KB) into LDS buffer `par`; LDS dest wave-uniform,
  // global src per-lane (global_load_lds semantics).
#define STAGE(t, par) do {                                                  \
    const char* _gb = (const char*)fb + (size_t)(t) * TILE_BYTES;           \
    float* _lb = emlds + (par) * LDS_TILE_F;                                \
    _Pragma("unroll")                                                       \
    for (int _k = 0; _k < 7; ++_k) {                                        \
      const char* _gp = _gb + _k * 1024 + lane * 16;                        \
      if (_gp > gclamp) _gp = gclamp;                                       \
      __builtin_amdgcn_global_load_lds((gu32*)_gp, (lu32*)(_lb + _k * 256), \
                                       16, 0, 0);                           \
    }                                                                       \
  } while (0)

  // ---- init (s = 0) ----
  float p0 = (lane < NT) ? (fb[lane] + trans[TAG_START * NT + lane]) : -1e30f;
  float c0 = p0;
  #pragma unroll
  for (int off = 32; off > 0; off >>= 1) c0 = fmaxf(c0, __shfl_xor(c0, off, 64));
  float w = (lane < NT) ? __expf(p0 - c0) : 0.f;
  int kacc = 6 * (len - 1);   // hoisted per-step 2^-6; renorm Ks added below

#define B4(p)                                                  \
  {                                                            \
    acc0 = fmaf(lane_bcast(w, 4 * (p) + 0), M##p.x, acc0);     \
    acc1 = fmaf(lane_bcast(w, 4 * (p) + 1), M##p.y, acc1);     \
    acc2 = fmaf(lane_bcast(w, 4 * (p) + 2), M##p.z, acc2);     \
    acc3 = fmaf(lane_bcast(w, 4 * (p) + 3), M##p.w, acc3);     \
  }

  // ---- forward recursion over double-buffered 32-step tiles ----
  const int Tt = (len + TILE - 1) / TILE;   // tiles covering steps 0..len-1
  STAGE(0, 0);
  STAGE(1, 1);                 // always address-valid (tiles are len-independent)
  bool pend7 = true;           // is a newer 7-load group outstanding at drain?
  int s = 1;
  for (int t = 0; t < Tt; ++t) {
    if (pend7) asm volatile("s_waitcnt vmcnt(7)" ::: "memory");
    else       asm volatile("s_waitcnt vmcnt(0)" ::: "memory");

    const float* bufX = emlds + (t & 1) * LDS_TILE_F;
    const int s0 = t * TILE;
    const int locF = s - s0;                    // 1 for t==0, else 0
    const int locE = min(TILE - 1, len - 1 - s0);

    // refill the 2-deep emission pipeline from this tile
    float emA = bufX[locF * NT + j];
    float efs = __expf(emA) * 0.015625f;        // exp(em)*2^-6, exact pow2
    emA = bufX[min(locF + 1, TILE - 1) * NT + j];

    for (int loc = locF; loc <= locE; ++loc, ++s) {
      float ef = efs;
      efs = __expf(emA) * 0.015625f;            // for step s+1
      emA = bufX[min(loc + 2, TILE - 1) * NT + j];  // 2 ahead (tail dups unused)

      float acc0 = 0.f, acc1 = 0.f, acc2 = 0.f, acc3 = 0.f;
      B4(0) B4(1) B4(2) B4(3) B4(4) B4(5) B4(6)
      B4(7) B4(8) B4(9) B4(10) B4(11) B4(12)
      float nv = ef * ((acc0 + acc1) + (acc2 + acc3));

      if ((s & 3) == 0) {      // exact pow2 re-center on lane 0's exponent
        float n0 = lane_bcast(nv, 0);
        int K = ((__float_as_int(n0) >> 23) & 0xff) - 127;
        nv = nv * __int_as_float((127 - K) << 23);
        kacc += K;
      }
      w = nv;
    }

    // buffer (t&1) fully consumed -> safe to refill with tile t+2
    pend7 = (t + 2 < NS / TILE) && ((t + 2) * TILE < len);
    if (pend7) STAGE(t + 2, t & 1);
  }

  // ---- final: forward_b = c0 + kacc*ln2 + log(sum_i w[i] * M[i][END]) ----
  {
    float acc0 = 0.f, acc1 = 0.f, acc2 = 0.f, acc3 = 0.f;
    B4(0) B4(1) B4(2) B4(3) B4(4) B4(5) B4(6)
    B4(7) B4(8) B4(9) B4(10) B4(11) B4(12)
    float fin  = __logf((acc0 + acc1) + (acc2 + acc3));  // valid on lane END
    float finU = lane_bcast(fin, TAG_END);
    double fwd = (double)c0 + (double)kacc * 0.6931471805599453 + (double)finU;

    // ---- gold path score ----
    float g = 0.f;
    for (int sg = lane; sg < len; sg += 64) {
      int tg = tags[b * NS + sg];
      int pv = (sg == 0) ? TAG_START : tags[b * NS + sg - 1];
      g += fb[sg * NT + tg] + trans[pv * NT + tg];
    }
    #pragma unroll
    for (int off = 32; off > 0; off >>= 1) g += __shfl_xor(g, off, 64);
    int lastTag = tags[b * NS + (len - 1)];
    double gold = (double)g + (double)trans[lastTag * NT + TAG_END];

    if (lane == 0) scores[b] = fwd - gold;
  }
#undef B4
#undef STAGE
}

extern "C" __global__ void __launch_bounds__(512)
crf_reduce_kernel(const double* __restrict__ scores, float* __restrict__ out)
{
  __shared__ double sh[8];
  int t = threadIdx.x;
  double x = scores[t];
  #pragma unroll
  for (int off = 32; off > 0; off >>= 1) x += __shfl_xor(x, off, 64);
  if ((t & 63) == 0) sh[t >> 6] = x;
  __syncthreads();
  if (t == 0) {
    double tot = 0.0;
    #pragma unroll
    for (int wv = 0; wv < 8; ++wv) tot += sh[wv];
    out[0] = (float)tot;
  }
}

extern "C" void kernel_launch(void* const* d_in, const int* in_sizes, int n_in,
                              void* d_out, int out_size, void* d_ws, size_t ws_size,
                              hipStream_t stream) {
  const float*         feats = (const float*)d_in[0];
  const unsigned char* mask  = (const unsigned char*)d_in[1];
  const int*           tags  = (const int*)d_in[2];
  const float*         trans = (const float*)d_in[3];
  double* scores = (double*)d_ws;   // 512 doubles = 4 KB scratch

  crf_batch_kernel<<<NB, 64, 0, stream>>>(feats, mask, tags, trans, scores);
  crf_reduce_kernel<<<1, 512, 0, stream>>>(scores, (float*)d_out);
}